// Round 1
// baseline (259.785 us; speedup 1.0000x reference)
//
#include <hip/hip_runtime.h>
#include <hip/hip_bf16.h>
#include <math.h>

typedef short bf16x8 __attribute__((ext_vector_type(8)));
typedef float f32x4 __attribute__((ext_vector_type(4)));

#define T_SEQ 2048
#define C_DIM 1024
#define H_HEADS 16
#define D_HEAD 64
#define BT 4096          // B*T
#define C3 3072
#define BH 32            // B*H

static __device__ inline unsigned short bf_bits(float f) {
    __hip_bfloat16 h = __float2bfloat16(f);
    unsigned short u;
    __builtin_memcpy(&u, &h, 2);
    return u;
}

// ---------------- cast f32 -> bf16, 4 elems/thread ----------------
__global__ void cast_f32_bf16(const float* __restrict__ in,
                              __hip_bfloat16* __restrict__ out, int n4) {
    int i = blockIdx.x * blockDim.x + threadIdx.x;
    if (i >= n4) return;
    float4 v = reinterpret_cast<const float4*>(in)[i];
    ushort4 o;
    o.x = bf_bits(v.x); o.y = bf_bits(v.y); o.z = bf_bits(v.z); o.w = bf_bits(v.w);
    reinterpret_cast<ushort4*>(out)[i] = o;
}

// ---------------- GEMM: Cout = A(M,K) * Bw(N,K)^T, bf16 MFMA ----------------
// 128x128 tile, BK=64, 256 threads (4 waves, 2x2 wave grid of 64x64)
template<int OUT_BF16>
__global__ __launch_bounds__(256) void gemm_bt(
    const __hip_bfloat16* __restrict__ A,
    const __hip_bfloat16* __restrict__ Bw,
    void* __restrict__ Cout, int M, int N, int K) {
    __shared__ __hip_bfloat16 As[128][72];
    __shared__ __hip_bfloat16 Bs[128][72];
    const int t = threadIdx.x;
    const int lane = t & 63, w = t >> 6;
    const int wr = w >> 1, wc = w & 1;
    const int l15 = lane & 15, lg = lane >> 4;
    const int m0 = blockIdx.y * 128, n0 = blockIdx.x * 128;
    const int srow = t >> 2, scol = (t & 3) * 16;

    f32x4 acc[4][4];
    f32x4 zero4 = {0.f, 0.f, 0.f, 0.f};
#pragma unroll
    for (int m = 0; m < 4; m++)
#pragma unroll
        for (int n = 0; n < 4; n++) acc[m][n] = zero4;

    for (int k0 = 0; k0 < K; k0 += 64) {
        __syncthreads();
#pragma unroll
        for (int i = 0; i < 2; i++) {
            int r = srow + i * 64;
            const uint4* ga = reinterpret_cast<const uint4*>(&A[(size_t)(m0 + r) * K + k0 + scol]);
            uint4 a0 = ga[0], a1 = ga[1];
            const uint4* gb = reinterpret_cast<const uint4*>(&Bw[(size_t)(n0 + r) * K + k0 + scol]);
            uint4 b0 = gb[0], b1 = gb[1];
            *reinterpret_cast<uint4*>(&As[r][scol]) = a0;
            *reinterpret_cast<uint4*>(&As[r][scol + 8]) = a1;
            *reinterpret_cast<uint4*>(&Bs[r][scol]) = b0;
            *reinterpret_cast<uint4*>(&Bs[r][scol + 8]) = b1;
        }
        __syncthreads();
#pragma unroll
        for (int kk = 0; kk < 2; kk++) {
            bf16x8 a[4], b[4];
            const int co = kk * 32 + lg * 8;
#pragma unroll
            for (int m = 0; m < 4; m++)
                a[m] = *reinterpret_cast<const bf16x8*>(&As[wr * 64 + m * 16 + l15][co]);
#pragma unroll
            for (int n = 0; n < 4; n++)
                b[n] = *reinterpret_cast<const bf16x8*>(&Bs[wc * 64 + n * 16 + l15][co]);
#pragma unroll
            for (int m = 0; m < 4; m++)
#pragma unroll
                for (int n = 0; n < 4; n++)
                    acc[m][n] = __builtin_amdgcn_mfma_f32_16x16x32_bf16(a[m], b[n], acc[m][n], 0, 0, 0);
        }
    }
#pragma unroll
    for (int m = 0; m < 4; m++)
#pragma unroll
        for (int n = 0; n < 4; n++)
#pragma unroll
            for (int jj = 0; jj < 4; jj++) {
                int row = m0 + wr * 64 + m * 16 + lg * 4 + jj;
                int col = n0 + wc * 64 + n * 16 + l15;
                float v = acc[m][n][jj];
                if (OUT_BF16)
                    ((__hip_bfloat16*)Cout)[(size_t)row * N + col] = __float2bfloat16(v);
                else
                    ((float*)Cout)[(size_t)row * N + col] = v;
            }
}

// ---------------- RoPE + scatter to (B,H,T,D), q scaled by 1/8 ----------------
__global__ void rope_scatter(const __hip_bfloat16* __restrict__ qkv,
                             const float* __restrict__ freqs,
                             __hip_bfloat16* __restrict__ q_s,
                             __hip_bfloat16* __restrict__ k_s,
                             __hip_bfloat16* __restrict__ v_s) {
    int idx = blockIdx.x * 256 + threadIdx.x;   // BT*H*32 threads
    int i = idx & 31;
    int h = (idx >> 5) & 15;
    int bt = idx >> 9;
    int b = bt >> 11;           // T=2048
    int tp = bt & 2047;
    float th = (float)tp * freqs[i];
    float sn = sinf(th), cs = cosf(th);
    size_t qoff = (size_t)bt * C3 + h * 64;
    float q1 = __bfloat162float(qkv[qoff + 2 * i]);
    float q2 = __bfloat162float(qkv[qoff + 2 * i + 1]);
    float k1 = __bfloat162float(qkv[qoff + C_DIM + 2 * i]);
    float k2 = __bfloat162float(qkv[qoff + C_DIM + 2 * i + 1]);
    size_t obase = ((size_t)(b * H_HEADS + h) * T_SEQ + tp) * D_HEAD;
    const float sc = 0.125f;    // 1/sqrt(D)
    q_s[obase + i]      = __float2bfloat16((q1 * cs - q2 * sn) * sc);
    q_s[obase + 32 + i] = __float2bfloat16((q1 * sn + q2 * cs) * sc);
    k_s[obase + i]      = __float2bfloat16(k1 * cs - k2 * sn);
    k_s[obase + 32 + i] = __float2bfloat16(k1 * sn + k2 * cs);
    v_s[obase + 2 * i]     = qkv[qoff + 2 * C_DIM + 2 * i];
    v_s[obase + 2 * i + 1] = qkv[qoff + 2 * C_DIM + 2 * i + 1];
}

// ---------------- flash attention: one block = (head, 64-row Q tile) ----------------
__global__ __launch_bounds__(256) void attn_kernel(
    const __hip_bfloat16* __restrict__ q_s,
    const __hip_bfloat16* __restrict__ k_s,
    const __hip_bfloat16* __restrict__ v_s,
    __hip_bfloat16* __restrict__ y) {
    __shared__ __hip_bfloat16 Vt[64][72];        // d-major transposed V tile
    __shared__ __hip_bfloat16 Pl[4][16][72];     // per-wave P tiles
    const int bh = blockIdx.y;
    const int qt = blockIdx.x;
    const int t = threadIdx.x, lane = t & 63, w = t >> 6;
    const int l15 = lane & 15, lg = lane >> 4;
    const size_t base = (size_t)bh * T_SEQ * D_HEAD;

    bf16x8 aq[2];
    const int qrow = qt * 64 + w * 16 + l15;
#pragma unroll
    for (int kk = 0; kk < 2; kk++)
        aq[kk] = *reinterpret_cast<const bf16x8*>(&q_s[base + (size_t)qrow * 64 + kk * 32 + lg * 8]);

    f32x4 zero4 = {0.f, 0.f, 0.f, 0.f};
    f32x4 o[4];
#pragma unroll
    for (int dc = 0; dc < 4; dc++) o[dc] = zero4;
    float mrow[4], lrow[4];
#pragma unroll
    for (int jj = 0; jj < 4; jj++) { mrow[jj] = -INFINITY; lrow[jj] = 0.f; }

    for (int kt = 0; kt <= qt; kt++) {
        // ---- S = Q K^T (pre-scaled) ----
        f32x4 s[4];
#pragma unroll
        for (int c = 0; c < 4; c++) {
            s[c] = zero4;
#pragma unroll
            for (int kk = 0; kk < 2; kk++) {
                bf16x8 bk = *reinterpret_cast<const bf16x8*>(
                    &k_s[base + (size_t)(kt * 64 + c * 16 + l15) * 64 + kk * 32 + lg * 8]);
                s[c] = __builtin_amdgcn_mfma_f32_16x16x32_bf16(aq[kk], bk, s[c], 0, 0, 0);
            }
        }
        // ---- causal mask (diagonal tile only) ----
        if (kt == qt) {
#pragma unroll
            for (int c = 0; c < 4; c++)
#pragma unroll
                for (int jj = 0; jj < 4; jj++) {
                    int qr = qt * 64 + w * 16 + lg * 4 + jj;
                    int kc = kt * 64 + c * 16 + l15;
                    if (kc > qr) s[c][jj] = -INFINITY;
                }
        }
        // ---- online softmax ----
        float scl[4];
#pragma unroll
        for (int jj = 0; jj < 4; jj++) {
            float mx = fmaxf(fmaxf(s[0][jj], s[1][jj]), fmaxf(s[2][jj], s[3][jj]));
#pragma unroll
            for (int d = 1; d < 16; d <<= 1) mx = fmaxf(mx, __shfl_xor(mx, d));
            float mnew = fmaxf(mrow[jj], mx);
            scl[jj] = expf(mrow[jj] - mnew);
            mrow[jj] = mnew;
        }
        __syncthreads();   // previous PV reads of Vt done
        float rs[4] = {0.f, 0.f, 0.f, 0.f};
#pragma unroll
        for (int c = 0; c < 4; c++)
#pragma unroll
            for (int jj = 0; jj < 4; jj++) {
                float p = expf(s[c][jj] - mrow[jj]);
                rs[jj] += p;
                Pl[w][lg * 4 + jj][c * 16 + l15] = __float2bfloat16(p);
            }
#pragma unroll
        for (int jj = 0; jj < 4; jj++) {
            float r = rs[jj];
#pragma unroll
            for (int d = 1; d < 16; d <<= 1) r += __shfl_xor(r, d);
            lrow[jj] = lrow[jj] * scl[jj] + r;
        }
        // ---- stage V transposed ----
        {
            int kv = t >> 2, dstart = (t & 3) * 16;
            const uint4* gv = reinterpret_cast<const uint4*>(
                &v_s[base + (size_t)(kt * 64 + kv) * 64 + dstart]);
            uint4 v0 = gv[0], v1 = gv[1];
            const __hip_bfloat16* pv = reinterpret_cast<const __hip_bfloat16*>(&v0);
#pragma unroll
            for (int di = 0; di < 8; di++) Vt[dstart + di][kv] = pv[di];
            pv = reinterpret_cast<const __hip_bfloat16*>(&v1);
#pragma unroll
            for (int di = 0; di < 8; di++) Vt[dstart + 8 + di][kv] = pv[di];
        }
        __syncthreads();
        // ---- rescale O, then O += P V ----
#pragma unroll
        for (int dc = 0; dc < 4; dc++)
#pragma unroll
            for (int jj = 0; jj < 4; jj++) o[dc][jj] *= scl[jj];
#pragma unroll
        for (int kk = 0; kk < 2; kk++) {
            bf16x8 ap = *reinterpret_cast<const bf16x8*>(&Pl[w][l15][kk * 32 + lg * 8]);
#pragma unroll
            for (int dc = 0; dc < 4; dc++) {
                bf16x8 bv = *reinterpret_cast<const bf16x8*>(&Vt[dc * 16 + l15][kk * 32 + lg * 8]);
                o[dc] = __builtin_amdgcn_mfma_f32_16x16x32_bf16(ap, bv, o[dc], 0, 0, 0);
            }
        }
    }
    // ---- write y in (B,T,C) ----
    const int b = bh >> 4, h = bh & 15;
#pragma unroll
    for (int dc = 0; dc < 4; dc++)
#pragma unroll
        for (int jj = 0; jj < 4; jj++) {
            int tq = qt * 64 + w * 16 + lg * 4 + jj;
            int col = h * 64 + dc * 16 + l15;
            float v = o[dc][jj] / lrow[jj];
            y[(size_t)(b * T_SEQ + tq) * C_DIM + col] = __float2bfloat16(v);
        }
}

// ---------------- LayerNorm over C=1024, one block per row ----------------
__global__ __launch_bounds__(256) void ln_kernel(const float* __restrict__ y2,
                                                 const float* __restrict__ wgt,
                                                 const float* __restrict__ bias,
                                                 float* __restrict__ out) {
    const int row = blockIdx.x;
    const int t = threadIdx.x;
    float4 v = reinterpret_cast<const float4*>(y2 + (size_t)row * C_DIM)[t];
    float s = v.x + v.y + v.z + v.w;
    float s2 = v.x * v.x + v.y * v.y + v.z * v.z + v.w * v.w;
#pragma unroll
    for (int d = 1; d < 64; d <<= 1) {
        s += __shfl_xor(s, d);
        s2 += __shfl_xor(s2, d);
    }
    __shared__ float ps[4], ps2[4];
    const int lane = t & 63, w = t >> 6;
    if (lane == 0) { ps[w] = s; ps2[w] = s2; }
    __syncthreads();
    s = ps[0] + ps[1] + ps[2] + ps[3];
    s2 = ps2[0] + ps2[1] + ps2[2] + ps2[3];
    float mean = s * (1.f / C_DIM);
    float var = s2 * (1.f / C_DIM) - mean * mean;
    float inv = rsqrtf(var + 1e-5f);
    float4 wv = reinterpret_cast<const float4*>(wgt)[t];
    float4 bv = reinterpret_cast<const float4*>(bias)[t];
    float4 ov;
    ov.x = (v.x - mean) * inv * wv.x + bv.x;
    ov.y = (v.y - mean) * inv * wv.y + bv.y;
    ov.z = (v.z - mean) * inv * wv.z + bv.z;
    ov.w = (v.w - mean) * inv * wv.w + bv.w;
    reinterpret_cast<float4*>(out + (size_t)row * C_DIM)[t] = ov;
}

extern "C" void kernel_launch(void* const* d_in, const int* in_sizes, int n_in,
                              void* d_out, int out_size, void* d_ws, size_t ws_size,
                              hipStream_t stream) {
    const float* x      = (const float*)d_in[0];
    const float* freqs  = (const float*)d_in[1];
    const float* W_attn = (const float*)d_in[2];
    const float* W_proj = (const float*)d_in[3];
    const float* lnw    = (const float*)d_in[4];
    const float* lnb    = (const float*)d_in[5];
    float* out = (float*)d_out;
    char* ws = (char*)d_ws;

    __hip_bfloat16* xb   = (__hip_bfloat16*)(ws);                 // 8.4 MB
    __hip_bfloat16* Wab  = (__hip_bfloat16*)(ws + 8388608);       // 6.3 MB
    __hip_bfloat16* Wpb  = (__hip_bfloat16*)(ws + 14680064);      // 2.1 MB
    __hip_bfloat16* qkvb = (__hip_bfloat16*)(ws + 16777216);      // 25.2 MB
    __hip_bfloat16* q_s  = (__hip_bfloat16*)(ws + 41943040);      // 8.4 MB
    __hip_bfloat16* k_s  = (__hip_bfloat16*)(ws + 50331648);      // 8.4 MB
    __hip_bfloat16* v_s  = (__hip_bfloat16*)(ws + 58720256);      // 8.4 MB
    __hip_bfloat16* y_at = (__hip_bfloat16*)(ws + 67108864);      // 8.4 MB
    float*          y2   = (float*)(ws + 75497472);               // 16.8 MB

    // casts
    cast_f32_bf16<<<(BT * C_DIM / 4) / 256, 256, 0, stream>>>(x, xb, BT * C_DIM / 4);
    cast_f32_bf16<<<(C3 * C_DIM / 4) / 256, 256, 0, stream>>>(W_attn, Wab, C3 * C_DIM / 4);
    cast_f32_bf16<<<(C_DIM * C_DIM / 4) / 256, 256, 0, stream>>>(W_proj, Wpb, C_DIM * C_DIM / 4);

    // qkv = x @ W_attn^T
    gemm_bt<1><<<dim3(C3 / 128, BT / 128), 256, 0, stream>>>(xb, Wab, qkvb, BT, C3, C_DIM);

    // rope + scatter
    rope_scatter<<<(BT * H_HEADS * 32) / 256, 256, 0, stream>>>(qkvb, freqs, q_s, k_s, v_s);

    // attention
    attn_kernel<<<dim3(T_SEQ / 64, BH), 256, 0, stream>>>(q_s, k_s, v_s, y_at);

    // proj
    gemm_bt<0><<<dim3(C_DIM / 128, BT / 128), 256, 0, stream>>>(y_at, Wpb, y2, BT, C_DIM, C_DIM);

    // layernorm
    ln_kernel<<<BT, 256, 0, stream>>>(y2, lnw, lnb, out);
}